// Round 1
// baseline (119.518 us; speedup 1.0000x reference)
//
#include <hip/hip_runtime.h>
#include <hip/hip_bf16.h>
#include <math.h>

#define TILE   16
#define HALO   18          // TILE + 2 halo
#define PITCH  19          // padded row pitch for feat planes
#define PLANE  (HALO*PITCH) // 342 floats per channel plane
#define NLVL   16
#define NPIX   (HALO*HALO)  // 324
#define CMAX   400          // corner scratch slots per buffer (need <=361)

// ---------------- prep kernel: styles, dcoef, fused weights W2, res table --------
// ws layout (floats): [0..16) res_tab, [32..32+3456) W2[b][o][c][ky][kx]
__global__ __launch_bounds__(256) void prep_kernel(
    const float* __restrict__ s,        // (4,512)
    const float* __restrict__ weight,   // (3,32,3,3) = 864
    const float* __restrict__ affine_w, // (32,512)
    const float* __restrict__ affine_b, // (32,)
    float* __restrict__ ws)
{
    __shared__ float styles[128];
    __shared__ float dcoef[12];
    int tid = threadIdx.x;

    // styles[b*32+c] = dot(s[b,:], affine_w[c,:]) / sqrt(512) + affine_b[c]
    {
        int p    = tid >> 1;    // 0..127 -> (b,c)
        int half = tid & 1;     // k-range split
        int b = p >> 5, c = p & 31;
        const float4* sv = (const float4*)(s + b*512 + half*256);
        const float4* wv = (const float4*)(affine_w + c*512 + half*256);
        float acc = 0.f;
        #pragma unroll 8
        for (int k = 0; k < 64; ++k) {
            float4 a = sv[k], w = wv[k];
            acc += a.x*w.x + a.y*w.y + a.z*w.z + a.w*w.w;
        }
        acc += __shfl_xor(acc, 1);
        if (half == 0)
            styles[p] = acc * 0.044194173824159216f + affine_b[c];
    }
    // res table — replicate numpy float64 math, cast to fp32
    if (tid < 16) {
        double g = exp((log(512.0) - log(16.0)) / 15.0);
        ws[tid] = (float)(16.0 * pow(g, (double)tid));
    }
    __syncthreads();

    // dcoef[b*3+o] = rsqrt( sum_{c,k} (weight[o,c,k]*styles[b,c])^2 + 1e-8 )
    if (tid < 12) {
        int b = tid / 3, o = tid % 3;
        float sum = 0.f;
        for (int c = 0; c < 32; ++c) {
            float st = styles[b*32 + c];
            #pragma unroll
            for (int k = 0; k < 9; ++k) {
                float w = weight[o*288 + c*9 + k] * st;
                sum = fmaf(w, w, sum);
            }
        }
        dcoef[tid] = 1.0f / sqrtf(sum + 1e-8f);
    }
    __syncthreads();

    // W2[b][o][c][ky][kx] = weight * styles[b,c] * dcoef[b,o]
    for (int t = tid; t < 4*864; t += 256) {
        int b = t / 864, r = t % 864;
        int o = r / 288;
        int c = (r % 288) / 9;
        ws[32 + t] = weight[r] * styles[b*32 + c] * dcoef[b*3 + o];
    }
}

// ---------------- main fused kernel ----------------
__global__ __launch_bounds__(256, 3) void main_kernel(
    const float* __restrict__ tables,  // (4,16,65536,2)
    const float* __restrict__ ws,
    const float* __restrict__ bias,    // (3,)
    float* __restrict__ out)           // (4,3,512,512)
{
    __shared__ float  feat[32 * PLANE];     // 43776 B, raw hash features
    __shared__ float2 corners[2][CMAX];     // 6400 B, per-level corner grid (dbuf)

    const int blk   = blockIdx.x;
    const int b     = blk >> 10;
    const int trem  = blk & 1023;
    const int tileY = trem >> 5, tileX = trem & 31;
    const int gx0 = tileX*TILE - 1, gy0 = tileY*TILE - 1;
    const int tid = threadIdx.x;

    // valid (in-image) halo pixel bounds
    const int vx_lo = max(gx0, 0), vx_hi = min(gx0 + 17, 511);
    const int vy_lo = max(gy0, 0), vy_hi = min(gy0 + 17, 511);

    const float2* tbl_base = (const float2*)tables;

    // ---- per-level param computation (uniform across block) ----
    auto level_params = [&](float res, int& ixlo, int& iylo, int& nx, int& ny) {
        float r512 = res * (1.0f/512.0f);
        int xlo = (int)floorf((vx_lo + 0.5f) * r512);
        int xhi = (int)floorf((vx_hi + 0.5f) * r512);
        int ylo = (int)floorf((vy_lo + 0.5f) * r512);
        int yhi = (int)floorf((vy_hi + 0.5f) * r512);
        ixlo = xlo; iylo = ylo;
        nx = xhi - xlo + 2; ny = yhi - ylo + 2;   // corners grid dims (<=19 each)
    };

    // ---- issue corner gathers for a level into registers ----
    auto issue_fetch = [&](int lvl, int ixlo, int iylo, int nx, int ny,
                           float2* regs, int* slots) {
        const float2* tbl = tbl_base + ((size_t)(b*16 + lvl) << 16);
        int row0 = tid >> 5, col = tid & 31;
        #pragma unroll
        for (int r = 0; r < 3; ++r) {
            int row = row0 + (r << 3);
            slots[r] = -1;
            if (col < nx && row < ny) {
                uint32_t cx = (uint32_t)(ixlo + col);
                uint32_t cy = (uint32_t)(iylo + row);
                uint32_t h  = cx ^ (cy * 2654435761u);
                regs[r]  = tbl[h & 65535u];
                slots[r] = row*nx + col;
            }
        }
    };

    // ================= Phase A: features =================
    int ixlo, iylo, nx, ny;
    float res_cur = ws[0];
    level_params(res_cur, ixlo, iylo, nx, ny);
    {
        float2 regs[3]; int slots[3];
        issue_fetch(0, ixlo, iylo, nx, ny, regs, slots);
        #pragma unroll
        for (int r = 0; r < 3; ++r)
            if (slots[r] >= 0) corners[0][slots[r]] = regs[r];
    }
    __syncthreads();

    for (int l = 0; l < NLVL; ++l) {
        // issue prefetch for level l+1 (loads stay in flight during compute)
        float2 regs[3]; int slots[3];
        slots[0] = slots[1] = slots[2] = -1;
        int nixlo = 0, niylo = 0, nnx = 0, nny = 0;
        float res_next = 0.f;
        if (l + 1 < NLVL) {
            res_next = ws[l + 1];
            level_params(res_next, nixlo, niylo, nnx, nny);
            issue_fetch(l + 1, nixlo, niylo, nnx, nny, regs, slots);
        }

        // bilinear features for level l from corners[l&1]
        {
            const float2* cbuf = corners[l & 1];
            float r512 = res_cur * (1.0f/512.0f);
            float* fp0 = feat + (2*l)*PLANE;
            float* fp1 = fp0 + PLANE;
            #pragma unroll
            for (int it = 0; it < 2; ++it) {
                int p = tid + it*256;
                if (p < NPIX) {
                    int hy = p / HALO, hx = p - hy*HALO;
                    int gy = gy0 + hy, gx = gx0 + hx;
                    float f0 = 0.f, f1 = 0.f;
                    if ((unsigned)gx < 512u && (unsigned)gy < 512u) {
                        float px = (gx + 0.5f) * r512;
                        float py = (gy + 0.5f) * r512;
                        float pxf = floorf(px), pyf = floorf(py);
                        float fx = px - pxf, fy = py - pyf;
                        int sx = (int)pxf - ixlo;
                        int sy = (int)pyf - iylo;
                        int s00 = sy*nx + sx;
                        float2 c00 = cbuf[s00],      c10 = cbuf[s00+1];
                        float2 c01 = cbuf[s00+nx],   c11 = cbuf[s00+nx+1];
                        float ux = 1.f - fx, uy = 1.f - fy;
                        float w00 = ux*uy, w10 = fx*uy, w01 = ux*fy, w11 = fx*fy;
                        f0 = w00*c00.x + w10*c10.x + w01*c01.x + w11*c11.x;
                        f1 = w00*c00.y + w10*c10.y + w01*c01.y + w11*c11.y;
                    }
                    fp0[hy*PITCH + hx] = f0;
                    fp1[hy*PITCH + hx] = f1;
                }
            }
        }

        // land the prefetched corners (vmcnt wait happens here, after compute)
        #pragma unroll
        for (int r = 0; r < 3; ++r)
            if (slots[r] >= 0) corners[(l + 1) & 1][slots[r]] = regs[r];
        __syncthreads();

        ixlo = nixlo; iylo = niylo; nx = nnx; ny = nny; res_cur = res_next;
    }

    // ================= Phase B: 3x3 conv, 32->3 channels =================
    const int ty = tid >> 4, tx = tid & 15;
    const int gy = tileY*TILE + ty, gx = tileX*TILE + tx;

    const float* W = ws + 32 + b*864;   // W2[o][c][ky][kx], o stride 288, c stride 9
    float acc0 = bias[0], acc1 = bias[1], acc2 = bias[2];
    const int fb = ty*PITCH + tx;

    #pragma unroll
    for (int c = 0; c < 32; ++c) {
        const float* Wc = W + c*9;
        const float* fc = feat + c*PLANE + fb;
        #pragma unroll
        for (int ky = 0; ky < 3; ++ky) {
            #pragma unroll
            for (int kx = 0; kx < 3; ++kx) {
                float f = fc[ky*PITCH + kx];
                float w0 = Wc[ky*3 + kx];
                float w1 = Wc[288 + ky*3 + kx];
                float w2 = Wc[576 + ky*3 + kx];
                acc0 = fmaf(w0, f, acc0);
                acc1 = fmaf(w1, f, acc1);
                acc2 = fmaf(w2, f, acc2);
            }
        }
    }
    acc0 = fminf(fmaxf(acc0, -256.f), 256.f);
    acc1 = fminf(fmaxf(acc1, -256.f), 256.f);
    acc2 = fminf(fmaxf(acc2, -256.f), 256.f);

    const int base = (gy << 9) + gx;
    out[((b*3 + 0) << 18) + base] = acc0;
    out[((b*3 + 1) << 18) + base] = acc1;
    out[((b*3 + 2) << 18) + base] = acc2;
}

extern "C" void kernel_launch(void* const* d_in, const int* in_sizes, int n_in,
                              void* d_out, int out_size, void* d_ws, size_t ws_size,
                              hipStream_t stream) {
    const float* x        = (const float*)d_in[0];
    const float* s        = (const float*)d_in[1];
    const float* weight   = (const float*)d_in[2];
    const float* affine_w = (const float*)d_in[3];
    const float* affine_b = (const float*)d_in[4];
    const float* bias     = (const float*)d_in[5];
    float* outp = (float*)d_out;
    float* wsf  = (float*)d_ws;

    prep_kernel<<<1, 256, 0, stream>>>(s, weight, affine_w, affine_b, wsf);
    main_kernel<<<4096, 256, 0, stream>>>(x, wsf, bias, outp);
}

// Round 2
// 80.239 us; speedup vs baseline: 1.4895x; 1.4895x over previous
//
#include <hip/hip_runtime.h>
#include <hip/hip_bf16.h>
#include <math.h>

#define TILE_X 16
#define TILE_Y 32
#define HALO_X 18
#define HALO_Y 34
#define NPIX   (HALO_X*HALO_Y)   // 612
#define NLVL   16
#define CMAX   720               // max corners per level: nx<=20, ny<=36

// ---------------- prep kernel ----------------
// ws layout (floats): [0..16) res_tab, [32..32+3456) W2[b][o][c][ky][kx]
__global__ __launch_bounds__(512) void prep_kernel(
    const float* __restrict__ s,        // (4,512)
    const float* __restrict__ weight,   // (3,32,3,3) = 864
    const float* __restrict__ affine_w, // (32,512)
    const float* __restrict__ affine_b, // (32,)
    float* __restrict__ ws)
{
    __shared__ float styles[128];
    __shared__ float dcoef[12];
    int tid = threadIdx.x;

    // styles[b*32+c] = dot(s[b,:], affine_w[c,:]) / sqrt(512) + affine_b[c]
    {
        int p = tid >> 2;      // 0..127 -> (b,c)
        int q = tid & 3;       // quarter of k-range
        int b = p >> 5, c = p & 31;
        const float4* sv = (const float4*)(s + b*512 + q*128);
        const float4* wv = (const float4*)(affine_w + c*512 + q*128);
        float acc = 0.f;
        #pragma unroll
        for (int k = 0; k < 32; ++k) {
            float4 a = sv[k], w = wv[k];
            acc += a.x*w.x + a.y*w.y + a.z*w.z + a.w*w.w;
        }
        acc += __shfl_xor(acc, 1);
        acc += __shfl_xor(acc, 2);
        if (q == 0)
            styles[p] = acc * 0.044194173824159216f + affine_b[c];
    }
    // res table — replicate numpy float64 math, cast to fp32
    if (tid < 16) {
        double g = exp((log(512.0) - log(16.0)) / 15.0);
        ws[tid] = (float)(16.0 * pow(g, (double)tid));
    }
    __syncthreads();

    if (tid < 12) {
        int b = tid / 3, o = tid % 3;
        float sum = 0.f;
        for (int c = 0; c < 32; ++c) {
            float st = styles[b*32 + c];
            #pragma unroll
            for (int k = 0; k < 9; ++k) {
                float w = weight[o*288 + c*9 + k] * st;
                sum = fmaf(w, w, sum);
            }
        }
        dcoef[tid] = 1.0f / sqrtf(sum + 1e-8f);
    }
    __syncthreads();

    for (int t = tid; t < 4*864; t += 512) {
        int b = t / 864, r = t % 864;
        int o = r / 288;
        int c = (r % 288) / 9;
        ws[32 + t] = weight[r] * styles[b*32 + c] * dcoef[b*3 + o];
    }
}

// ---------------- main fused kernel ----------------
struct LP { int ixlo, iylo, nx, ncorn; unsigned magic; };

__global__ __launch_bounds__(256, 6) void main_kernel(
    const float* __restrict__ tables,  // (4,16,65536,2)
    const float* __restrict__ ws,
    const float* __restrict__ bias,    // (3,)
    float* __restrict__ out)           // (4,3,512,512)
{
    __shared__ float2 feat2[2][NPIX];      // 9792 B  (level's 2 channels, dbuf)
    __shared__ float2 corners[2][CMAX];    // 11520 B (corner grid, dbuf)

    const int blk   = blockIdx.x;
    const int b     = blk >> 9;
    const int trem  = blk & 511;
    const int tileY = trem >> 5, tileX = trem & 31;   // 16 y-tiles, 32 x-tiles
    const int gx0 = tileX*TILE_X - 1, gy0 = tileY*TILE_Y - 1;
    const int tid = threadIdx.x;

    const int vx_lo = max(gx0, 0), vx_hi = min(gx0 + HALO_X - 1, 511);
    const int vy_lo = max(gy0, 0), vy_hi = min(gy0 + HALO_Y - 1, 511);

    const float2* tbl_base = (const float2*)tables;

    auto level_params = [&](float res) {
        LP lp;
        float r512 = res * (1.0f/512.0f);
        int xlo = (int)floorf((vx_lo + 0.5f) * r512);
        int xhi = (int)floorf((vx_hi + 0.5f) * r512);
        int ylo = (int)floorf((vy_lo + 0.5f) * r512);
        int yhi = (int)floorf((vy_hi + 0.5f) * r512);
        lp.ixlo = xlo; lp.iylo = ylo;
        lp.nx = xhi - xlo + 2;
        int ny = yhi - ylo + 2;
        lp.ncorn = lp.nx * ny;
        lp.magic = 65536u / (unsigned)lp.nx + 1u;   // exact for c<=736, nx<=36
        return lp;
    };

    auto issue_fetch = [&](int lvl, const LP& lp, float2* regs, int* slots) {
        const float2* tbl = tbl_base + ((size_t)((b << 4) + lvl) << 16);
        #pragma unroll
        for (int r = 0; r < 3; ++r) {
            int c = tid + (r << 8);
            slots[r] = -1;
            if (c < lp.ncorn) {
                unsigned row = ((unsigned)c * lp.magic) >> 16;
                unsigned col = (unsigned)c - row * (unsigned)lp.nx;
                unsigned cx = (unsigned)(lp.ixlo + (int)col);
                unsigned cy = (unsigned)(lp.iylo + (int)row);
                unsigned h  = cx ^ (cy * 2654435761u);
                regs[r]  = tbl[h & 65535u];
                slots[r] = c;
            }
        }
    };

    // conv state: 2 pixels per thread (y-pair), 3 output channels
    const int ty = tid >> 4;     // 0..15 -> output rows 2ty, 2ty+1
    const int tx = tid & 15;
    const float* W = ws + 32 + b*864;    // [o][c][ky][kx]; o stride 288, c stride 9
    float acc00 = bias[0], acc01 = bias[1], acc02 = bias[2];
    float acc10 = bias[0], acc11 = bias[1], acc12 = bias[2];

    // ---- prologue: fetch level 0 corners ----
    float res_cur = ws[0];
    LP lp = level_params(res_cur);
    {
        float2 regs[3]; int slots[3];
        issue_fetch(0, lp, regs, slots);
        #pragma unroll
        for (int r = 0; r < 3; ++r)
            if (slots[r] >= 0) corners[0][slots[r]] = regs[r];
    }
    __syncthreads();

    #pragma unroll 2
    for (int l = 0; l < NLVL; ++l) {
        const int buf = l & 1;

        // prefetch level l+1 corners into registers (loads fly during bilinear)
        float2 regs[3]; int slots[3];
        slots[0] = slots[1] = slots[2] = -1;
        LP lpn; lpn.ixlo = 0; lpn.iylo = 0; lpn.nx = 2; lpn.ncorn = 0; lpn.magic = 32769u;
        float res_next = 0.f;
        if (l + 1 < NLVL) {
            res_next = ws[l + 1];
            lpn = level_params(res_next);
            issue_fetch(l + 1, lpn, regs, slots);
        }

        // bilinear features for level l -> feat2[buf]
        {
            const float2* cbuf = corners[buf];
            float r512 = res_cur * (1.0f/512.0f);
            #pragma unroll
            for (int it = 0; it < 3; ++it) {
                int p = tid + (it << 8);
                if (p < NPIX) {
                    int hy = p / HALO_X, hx = p - hy*HALO_X;
                    int gy = gy0 + hy, gx = gx0 + hx;
                    float2 f; f.x = 0.f; f.y = 0.f;
                    if ((unsigned)gx < 512u && (unsigned)gy < 512u) {
                        float px = (gx + 0.5f) * r512;
                        float py = (gy + 0.5f) * r512;
                        float pxf = floorf(px), pyf = floorf(py);
                        float fx = px - pxf, fy = py - pyf;
                        int s00 = ((int)pyf - lp.iylo)*lp.nx + ((int)pxf - lp.ixlo);
                        float2 c00 = cbuf[s00],        c10 = cbuf[s00 + 1];
                        float2 c01 = cbuf[s00 + lp.nx], c11 = cbuf[s00 + lp.nx + 1];
                        float ux = 1.f - fx, uy = 1.f - fy;
                        float w00 = ux*uy, w10 = fx*uy, w01 = ux*fy, w11 = fx*fy;
                        f.x = w00*c00.x + w10*c10.x + w01*c01.x + w11*c11.x;
                        f.y = w00*c00.y + w10*c10.y + w01*c01.y + w11*c11.y;
                    }
                    feat2[buf][p] = f;
                }
            }
        }

        // land prefetched corners (vmcnt drains here, after bilinear compute)
        #pragma unroll
        for (int r = 0; r < 3; ++r)
            if (slots[r] >= 0) corners[buf ^ 1][slots[r]] = regs[r];
        __syncthreads();

        // conv partial accumulation for this level's 2 channels
        {
            const float2* fb = feat2[buf] + (ty*2)*HALO_X + tx;
            float2 v[4][3];
            #pragma unroll
            for (int r = 0; r < 4; ++r) {
                v[r][0] = fb[r*HALO_X + 0];
                v[r][1] = fb[r*HALO_X + 1];
                v[r][2] = fb[r*HALO_X + 2];
            }
            const float* Wl = W + (2*l)*9;   // c = 2l
            #pragma unroll
            for (int ky = 0; ky < 3; ++ky) {
                #pragma unroll
                for (int kx = 0; kx < 3; ++kx) {
                    float w00 = Wl[      ky*3 + kx];   // o=0,c=2l
                    float w01 = Wl[  9 + ky*3 + kx];   // o=0,c=2l+1
                    float w10 = Wl[288 + ky*3 + kx];
                    float w11 = Wl[297 + ky*3 + kx];
                    float w20 = Wl[576 + ky*3 + kx];
                    float w21 = Wl[585 + ky*3 + kx];
                    float2 f0 = v[ky][kx];       // output row 2ty
                    float2 f1 = v[ky + 1][kx];   // output row 2ty+1
                    acc00 = fmaf(w00, f0.x, acc00); acc00 = fmaf(w01, f0.y, acc00);
                    acc01 = fmaf(w10, f0.x, acc01); acc01 = fmaf(w11, f0.y, acc01);
                    acc02 = fmaf(w20, f0.x, acc02); acc02 = fmaf(w21, f0.y, acc02);
                    acc10 = fmaf(w00, f1.x, acc10); acc10 = fmaf(w01, f1.y, acc10);
                    acc11 = fmaf(w10, f1.x, acc11); acc11 = fmaf(w11, f1.y, acc11);
                    acc12 = fmaf(w20, f1.x, acc12); acc12 = fmaf(w21, f1.y, acc12);
                }
            }
        }

        lp = lpn; res_cur = res_next;
    }

    // ---- epilogue: clamp + store 2 pixels x 3 channels ----
    acc00 = fminf(fmaxf(acc00, -256.f), 256.f);
    acc01 = fminf(fmaxf(acc01, -256.f), 256.f);
    acc02 = fminf(fmaxf(acc02, -256.f), 256.f);
    acc10 = fminf(fmaxf(acc10, -256.f), 256.f);
    acc11 = fminf(fmaxf(acc11, -256.f), 256.f);
    acc12 = fminf(fmaxf(acc12, -256.f), 256.f);

    const int gx = tileX*TILE_X + tx;
    const int gy = tileY*TILE_Y + ty*2;
    const int base0 = (gy << 9) + gx;
    const int base1 = base0 + 512;
    const int ob = (b*3) << 18;
    out[ob             + base0] = acc00;
    out[ob + (1<<18)   + base0] = acc01;
    out[ob + (2<<18)   + base0] = acc02;
    out[ob             + base1] = acc10;
    out[ob + (1<<18)   + base1] = acc11;
    out[ob + (2<<18)   + base1] = acc12;
}

extern "C" void kernel_launch(void* const* d_in, const int* in_sizes, int n_in,
                              void* d_out, int out_size, void* d_ws, size_t ws_size,
                              hipStream_t stream) {
    const float* x        = (const float*)d_in[0];
    const float* s        = (const float*)d_in[1];
    const float* weight   = (const float*)d_in[2];
    const float* affine_w = (const float*)d_in[3];
    const float* affine_b = (const float*)d_in[4];
    const float* bias     = (const float*)d_in[5];
    float* outp = (float*)d_out;
    float* wsf  = (float*)d_ws;

    prep_kernel<<<1, 512, 0, stream>>>(s, weight, affine_w, affine_b, wsf);
    main_kernel<<<2048, 256, 0, stream>>>(x, wsf, bias, outp);
}